// Round 2
// baseline (448.959 us; speedup 1.0000x reference)
//
#include <hip/hip_runtime.h>
#include <hip/hip_bf16.h>

// B=4, S=2048, D_MODEL=1024, H=16, HEAD=64. Inputs fp32, output fp32.
#define S_LEN 2048
#define DM    1024
#define NH    16
#define HD    64

typedef __attribute__((ext_vector_type(8))) short short8;   // 8 bf16 (MFMA A/B frag)
typedef __attribute__((ext_vector_type(4))) short short4v;  // 4 bf16 (8B store)
typedef __attribute__((ext_vector_type(4))) float f32x4;    // MFMA C/D frag

// fp32 -> bf16 RNE (weight/output paths)
__device__ __forceinline__ short f2bf(float f) {
    union { float f; unsigned u; } x; x.f = f;
    unsigned u = x.u;
    return (short)((u + 0x7FFFu + ((u >> 16) & 1u)) >> 16);
}
// round-half-up variants (2 VALU; bias negligible for continuous data)
__device__ __forceinline__ short f2bf_ru(float f) {
    return (short)((__float_as_uint(f) + 0x8000u) >> 16);
}
__device__ __forceinline__ unsigned pk2bf(float a, float b) {
    unsigned ua = __float_as_uint(a) + 0x8000u;
    unsigned ub = __float_as_uint(b) + 0x8000u;
    return (ua >> 16) | (ub & 0xFFFF0000u);
}
__device__ __forceinline__ float fexp2(float x) {
#if __has_builtin(__builtin_amdgcn_exp2f)
    return __builtin_amdgcn_exp2f(x);
#else
    return exp2f(x);
#endif
}
// async global->LDS, 16B per lane (wave-uniform base + lane*16 dest)
__device__ __forceinline__ void gload_lds16(const void* g, void* l) {
    __builtin_amdgcn_global_load_lds(
        (const __attribute__((address_space(1))) unsigned int*)g,
        (__attribute__((address_space(3))) unsigned int*)l, 16, 0, 0);
}

// ---------------------------------------------------------------------------
// Kernel 1: W [K][N] fp32 -> WT [N][K] bf16 for Wq/Wk/Wv (blockIdx.z)
// ---------------------------------------------------------------------------
__global__ void wt_kernel(const float* __restrict__ Wq, const float* __restrict__ Wk,
                          const float* __restrict__ Wv, short* __restrict__ wt_base) {
    __shared__ float t[32][33];
    const float* W = (blockIdx.z == 0) ? Wq : (blockIdx.z == 1 ? Wk : Wv);
    short* WT = wt_base + (size_t)blockIdx.z * DM * DM;
    int kb = blockIdx.x * 32, nb = blockIdx.y * 32;
    int tx = threadIdx.x, ty = threadIdx.y;  // 32 x 8
#pragma unroll
    for (int r = 0; r < 4; r++)
        t[ty + 8 * r][tx] = W[(size_t)(kb + ty + 8 * r) * DM + nb + tx];
    __syncthreads();
#pragma unroll
    for (int r = 0; r < 4; r++)
        WT[(size_t)(nb + ty + 8 * r) * DM + kb + tx] = f2bf(t[tx][ty + 8 * r]);
}

// ---------------------------------------------------------------------------
// Kernel 2: fused projections (z = 0:Q, 1:K, 2:V), software-pipelined.
// Tile 128x128, BK=32, LDS double-buffered, ONE barrier/iter. Latency-bound
// structure (R1 counters: MfmaUtil 13.6 / VALU 16.5 / HBM 11% / occ 33%), so:
//  - __launch_bounds__(256,5): 5 blocks/CU (5 x 32KB = 160KB LDS exact fit,
//    VGPR=64 permits 8 waves/SIMD) -> 20 waves/CU of TLP vs 12.
//  - staging (A float4 + B global_load_lds for tile t+1) issued FIRST after
//    the barrier, before frag ds_reads: max in-flight distance to the
//    convert/drain that consumes them (minimum-2-phase ordering).
// z<2: out head-major [b][h][s][64].  z==2: out transposed [b][h][64][S].
// Grid 1D (1536) chunked XCD swizzle: 8 N-tile siblings of one X row-panel
// are consecutive on the same XCD (R1: FETCH 396->67MB).
// ---------------------------------------------------------------------------
__global__ __launch_bounds__(256, 5) void projf_kernel(
        const float* __restrict__ Xq, const float* __restrict__ Xk,
        const float* __restrict__ Xv, const short* __restrict__ WT3,
        const float* __restrict__ bq, const float* __restrict__ bk,
        const float* __restrict__ bv,
        short* __restrict__ Qh, short* __restrict__ Kh, short* __restrict__ Vt,
        float qscale) {
    __shared__ __align__(16) short As[2][128 * 32];
    __shared__ __align__(16) short Bs[2][128 * 32];
    // ---- chunked bijective XCD swizzle: 1536 = 8 XCDs x 192 ----
    const int bid = blockIdx.x;
    const int swz = (bid & 7) * 192 + (bid >> 3);
    const int nx = swz & 7;          // n-tile (fastest in logical order)
    const int my = (swz >> 3) & 63;  // m-tile
    const int z  = swz >> 9;         // matrix select (8*64 = 512 per z)

    const float* X = (z == 0) ? Xq : (z == 1) ? Xk : Xv;
    const short* WT = WT3 + (size_t)z * DM * DM;
    const float* bias = (z == 0) ? bq : (z == 1) ? bk : bv;
    short* out = (z == 0) ? Qh : (z == 1) ? Kh : Vt;
    const float scale = (z == 0) ? qscale : 1.0f;
    const int mode = (z == 2);

    const int tid = threadIdx.x;
    const int lane = tid & 63, w = tid >> 6;
    const int l15 = lane & 15, quad = lane >> 4;
    const int n0 = nx * 128, m0 = my * 128;
    const int wm = (w & 1) * 64, wn = (w >> 1) * 64;
    const int arow = tid >> 3;          // A staging: 8 lanes/row
    const int ako  = (tid & 7) * 4;     // 4 floats (=4 bf16 out) per lane

    const float* xb = X + (size_t)m0 * DM;

    f32x4 acc[4][4];
#pragma unroll
    for (int i = 0; i < 4; i++)
#pragma unroll
        for (int j = 0; j < 4; j++) { acc[i][j][0] = 0.f; acc[i][j][1] = 0.f; acc[i][j][2] = 0.f; acc[i][j][3] = 0.f; }

    // ---- prologue: stage tile 0 into buf 0 ----
    float4 araw[4];
#pragma unroll
    for (int it = 0; it < 4; it++)
        araw[it] = *(const float4*)(xb + (size_t)(it * 32 + arow) * DM + ako);
#pragma unroll
    for (int it = 0; it < 2; it++) {
        int c = it * 256 + tid;
        int row = c >> 2, ko = (c & 3) * 8;
        gload_lds16(WT + (size_t)(n0 + row) * DM + ko, Bs[0] + c * 8);
    }
#pragma unroll
    for (int it = 0; it < 4; it++) {
        int row = it * 32 + arow;
        uint2 p; p.x = pk2bf(araw[it].x, araw[it].y); p.y = pk2bf(araw[it].z, araw[it].w);
        *(uint2*)(As[0] + row * 32 + ako) = p;
    }

    for (int t = 0; t < 32; t++) {
        const int bi = t & 1;
        const int kn = t * 32 + 32;     // next tile's k0
        __syncthreads();                // tile t staged; buf bi^1 free to overwrite

        if (t < 31) {                   // STAGE FIRST: next tile's loads in flight
#pragma unroll
            for (int it = 0; it < 4; it++)
                araw[it] = *(const float4*)(xb + (size_t)(it * 32 + arow) * DM + kn + ako);
#pragma unroll
            for (int it = 0; it < 2; it++) {
                int c = it * 256 + tid;
                int row = c >> 2, ko = (c & 3) * 8;
                gload_lds16(WT + (size_t)(n0 + row) * DM + kn + ko, Bs[bi ^ 1] + c * 8);
            }
        }

        short8 af[4], bf[4];
#pragma unroll
        for (int i = 0; i < 4; i++)
            af[i] = *(const short8*)(As[bi] + (wm + i * 16 + l15) * 32 + quad * 8);
#pragma unroll
        for (int j = 0; j < 4; j++)
            bf[j] = *(const short8*)(Bs[bi] + (wn + j * 16 + l15) * 32 + quad * 8);

#pragma unroll
        for (int i = 0; i < 4; i++)
#pragma unroll
            for (int j = 0; j < 4; j++)
                acc[i][j] = __builtin_amdgcn_mfma_f32_16x16x32_bf16(af[i], bf[j], acc[i][j], 0, 0, 0);

        if (t < 31) {                   // convert+write A for tile t+1 into buf^1
#pragma unroll
            for (int it = 0; it < 4; it++) {
                int row = it * 32 + arow;
                uint2 p; p.x = pk2bf(araw[it].x, araw[it].y); p.y = pk2bf(araw[it].z, araw[it].w);
                *(uint2*)(As[bi ^ 1] + row * 32 + ako) = p;
            }
        }
    }

    // ---- epilogue ----
#pragma unroll
    for (int j = 0; j < 4; j++) {
        int col = n0 + wn + j * 16 + l15;
        float bv_ = bias[col];
        int h = col >> 6, d = col & 63;
#pragma unroll
        for (int i = 0; i < 4; i++) {
            int rowbase = m0 + wm + i * 16 + quad * 4;
            int bb = rowbase >> 11, s0 = rowbase & 2047;
            if (mode == 0) {
#pragma unroll
                for (int r = 0; r < 4; r++)
                    out[((size_t)(bb * NH + h) * S_LEN + (s0 + r)) * HD + d] =
                        f2bf((acc[i][j][r] + bv_) * scale);
            } else {
                short4v pk;
#pragma unroll
                for (int r = 0; r < 4; r++) pk[r] = f2bf((acc[i][j][r] + bv_) * scale);
                *(short4v*)(out + ((size_t)(bb * NH + h) * HD + d) * S_LEN + s0) = pk;
            }
        }
    }
}

// ---------------------------------------------------------------------------
// Kernel 3: attention. Block = 256 thr (4 waves), q-tile 128 (wave: 2x16 rows).
// K/V tiles (64 keys) staged block-cooperatively via global_load_lds into
// double-buffered LDS ([half][row][32] 64B rows, m97 bank pattern); tile t+1
// issued at iter start, ONE __syncthreads per iter drains it ~a full body later.
// No-max softmax (Q pre-scaled by 0.125*log2e, exp2); P via wave-private LDS.
// Grid 1D (1024) chunked XCD swizzle: 16 q-tile siblings of one head's K/V
// are consecutive on the same XCD.
// ---------------------------------------------------------------------------
__global__ __launch_bounds__(256, 3) void attn_kernel(
        const short* __restrict__ Q, const short* __restrict__ K,
        const short* __restrict__ V, float* __restrict__ out) {
    __shared__ __align__(16) short Ks[2][2][64][32];  // [buf][half][key-row][32] 16KB
    __shared__ __align__(16) short Vs[2][2][64][32];  // [buf][half][d-row][32]   16KB
    __shared__ __align__(16) short ps[4][2][16 * 72]; // [wave][strip]            18KB
    // ---- chunked bijective XCD swizzle: 1024 = 8 XCDs x 128 ----
    const int bid = blockIdx.x;
    const int swz = (bid & 7) * 128 + (bid >> 3);
    const int qi = swz & 15;         // q-tile (fastest in logical order)
    const int h  = (swz >> 4) & 15;  // head
    const int b  = swz >> 8;         // batch (16*16 = 256 per b)

    const int tid = threadIdx.x;
    const int lane = tid & 63, w = tid >> 6;
    const int l15 = lane & 15, quad = lane >> 4;
    const int q0 = qi * 128;
    const size_t bh = (size_t)(b * NH + h);
    const short* qp = Q + bh * S_LEN * HD;
    const short* kp = K + bh * S_LEN * HD;
    const short* vp = V + bh * (size_t)HD * S_LEN;

    short8 qa[2][2];
#pragma unroll
    for (int s = 0; s < 2; s++) {
        const short* qr = qp + (size_t)(q0 + w * 32 + s * 16 + l15) * HD + quad * 8;
        qa[s][0] = *(const short8*)(qr);
        qa[s][1] = *(const short8*)(qr + 32);
    }

    f32x4 o[2][4];
    float lsum[2][4];
#pragma unroll
    for (int s = 0; s < 2; s++)
#pragma unroll
        for (int d = 0; d < 4; d++) {
            o[s][d][0] = 0.f; o[s][d][1] = 0.f; o[s][d][2] = 0.f; o[s][d][3] = 0.f;
            lsum[s][d] = 0.f;
        }

    auto stageKV = [&](int kt, int bi) {
        short* kd = &Ks[bi][0][0][0];
        short* vd = &Vs[bi][0][0][0];
#pragma unroll
        for (int it = 0; it < 2; it++) {
            int c = it * 256 + tid;                  // 512 slots x 16B = 8KB each
            int half = c >> 8, row = (c >> 2) & 63, chunk = c & 3;
            int co = half * 32 + chunk * 8;
            gload_lds16(kp + (size_t)(kt + row) * HD + co, kd + c * 8);
            gload_lds16(vp + (size_t)row * S_LEN + kt + co, vd + c * 8);
        }
    };

    stageKV(0, 0);

    for (int t = 0; t < 32; t++) {
        const int bi = t & 1;
        __syncthreads();                 // tile t ready (vmcnt drained); buf^1 free
        if (t < 31) stageKV((t + 1) << 6, bi ^ 1);   // issue next tile NOW

        // ---- K frags from LDS (shared by both strips) + QK^T ----
        short8 kf[4][2];
#pragma unroll
        for (int nb = 0; nb < 4; nb++) {
            kf[nb][0] = *(const short8*)(&Ks[bi][0][nb * 16 + l15][quad * 8]);
            kf[nb][1] = *(const short8*)(&Ks[bi][1][nb * 16 + l15][quad * 8]);
        }
        f32x4 sacc[2][4];
#pragma unroll
        for (int nb = 0; nb < 4; nb++)
#pragma unroll
            for (int s = 0; s < 2; s++) {
                f32x4 zz; zz[0] = 0.f; zz[1] = 0.f; zz[2] = 0.f; zz[3] = 0.f;
                zz = __builtin_amdgcn_mfma_f32_16x16x32_bf16(qa[s][0], kf[nb][0], zz, 0, 0, 0);
                sacc[s][nb] = __builtin_amdgcn_mfma_f32_16x16x32_bf16(qa[s][1], kf[nb][1], zz, 0, 0, 0);
            }
        // ---- P = exp2(S'); partial row-sums; P -> wave-private LDS ----
#pragma unroll
        for (int s = 0; s < 2; s++)
#pragma unroll
            for (int r = 0; r < 4; r++)
#pragma unroll
                for (int nb = 0; nb < 4; nb++) {
                    float p = fexp2(sacc[s][nb][r]);
                    lsum[s][r] += p;
                    ps[w][s][(quad * 4 + r) * 72 + nb * 16 + l15] = f2bf_ru(p);
                }
        asm volatile("s_waitcnt lgkmcnt(0)" ::: "memory");
        short8 pa[2][2];
#pragma unroll
        for (int s = 0; s < 2; s++) {
            pa[s][0] = *(const short8*)(&ps[w][s][l15 * 72 + quad * 8]);
            pa[s][1] = *(const short8*)(&ps[w][s][l15 * 72 + 32 + quad * 8]);
        }
        // ---- V frags from LDS + PV ----
#pragma unroll
        for (int dd = 0; dd < 4; dd++) {
            short8 v0 = *(const short8*)(&Vs[bi][0][dd * 16 + l15][quad * 8]);
            short8 v1 = *(const short8*)(&Vs[bi][1][dd * 16 + l15][quad * 8]);
#pragma unroll
            for (int s = 0; s < 2; s++) {
                o[s][dd] = __builtin_amdgcn_mfma_f32_16x16x32_bf16(pa[s][0], v0, o[s][dd], 0, 0, 0);
                o[s][dd] = __builtin_amdgcn_mfma_f32_16x16x32_bf16(pa[s][1], v1, o[s][dd], 0, 0, 0);
            }
        }
    }

    // ---- deferred l reduction + epilogue ----
#pragma unroll
    for (int s = 0; s < 2; s++) {
#pragma unroll
        for (int r = 0; r < 4; r++) {
            float l = lsum[s][r];
            l += __shfl_xor(l, 1);
            l += __shfl_xor(l, 2);
            l += __shfl_xor(l, 4);
            l += __shfl_xor(l, 8);
            lsum[s][r] = 1.f / l;
        }
        float* orow = out + ((size_t)b * S_LEN + q0 + w * 32 + s * 16 + quad * 4) * DM + h * HD + l15;
#pragma unroll
        for (int r = 0; r < 4; r++)
#pragma unroll
            for (int dd = 0; dd < 4; dd++)
                orow[(size_t)r * DM + dd * 16] = o[s][dd][r] * lsum[s][r];
    }
}

// ---------------------------------------------------------------------------
// ws (56.6 MB): [0,6.3M) WT x3 bf16 | Qh | Kh | Vt (16.8M each)
// ---------------------------------------------------------------------------
extern "C" void kernel_launch(void* const* d_in, const int* in_sizes, int n_in,
                              void* d_out, int out_size, void* d_ws, size_t ws_size,
                              hipStream_t stream) {
    const float* query  = (const float*)d_in[0];
    const float* key_in = (const float*)d_in[1];
    const float* value  = (const float*)d_in[2];
    const float* Wq = (const float*)d_in[3];
    const float* bq = (const float*)d_in[4];
    const float* Wk = (const float*)d_in[5];
    const float* bk = (const float*)d_in[6];
    const float* Wv = (const float*)d_in[7];
    const float* bv = (const float*)d_in[8];

    short* wt = (short*)d_ws;
    short* Qh = wt + 3 * 1048576;
    short* Kh = Qh + 8388608;
    short* Vt = Kh + 8388608;
    float* out = (float*)d_out;

    const float QSCALE = 0.125f * 1.44269504088896340736f;  // 1/sqrt(64) * log2(e)

    wt_kernel<<<dim3(32, 32, 3), dim3(32, 8), 0, stream>>>(Wq, Wk, Wv, wt);
    projf_kernel<<<dim3(1536), 256, 0, stream>>>(query, key_in, value, wt,
                                                 bq, bk, bv, Qh, Kh, Vt, QSCALE);
    attn_kernel<<<dim3(1024), 256, 0, stream>>>(Qh, Kh, Vt, out);
}

// Round 3
// 370.222 us; speedup vs baseline: 1.2127x; 1.2127x over previous
//
#include <hip/hip_runtime.h>
#include <hip/hip_bf16.h>

// B=4, S=2048, D_MODEL=1024, H=16, HEAD=64. Inputs fp32, output fp32.
#define S_LEN 2048
#define DM    1024
#define NH    16
#define HD    64

typedef __attribute__((ext_vector_type(8))) short short8;   // 8 bf16 (MFMA A/B frag)
typedef __attribute__((ext_vector_type(4))) short short4v;  // 4 bf16 (8B store)
typedef __attribute__((ext_vector_type(4))) float f32x4;    // MFMA C/D frag

// fp32 -> bf16 RNE (weight/output paths)
__device__ __forceinline__ short f2bf(float f) {
    union { float f; unsigned u; } x; x.f = f;
    unsigned u = x.u;
    return (short)((u + 0x7FFFu + ((u >> 16) & 1u)) >> 16);
}
// round-half-up variants (2 VALU; bias negligible for continuous data)
__device__ __forceinline__ short f2bf_ru(float f) {
    return (short)((__float_as_uint(f) + 0x8000u) >> 16);
}
__device__ __forceinline__ unsigned pk2bf(float a, float b) {
    unsigned ua = __float_as_uint(a) + 0x8000u;
    unsigned ub = __float_as_uint(b) + 0x8000u;
    return (ua >> 16) | (ub & 0xFFFF0000u);
}
__device__ __forceinline__ float fexp2(float x) {
#if __has_builtin(__builtin_amdgcn_exp2f)
    return __builtin_amdgcn_exp2f(x);
#else
    return exp2f(x);
#endif
}
// async global->LDS, 16B per lane (wave-uniform base + lane*16 dest)
__device__ __forceinline__ void gload_lds16(const void* g, void* l) {
    __builtin_amdgcn_global_load_lds(
        (const __attribute__((address_space(1))) unsigned int*)g,
        (__attribute__((address_space(3))) unsigned int*)l, 16, 0, 0);
}

// ---------------------------------------------------------------------------
// Kernel 1: W [K][N] fp32 -> WT [N][K] bf16 for Wq/Wk/Wv (blockIdx.z)
// ---------------------------------------------------------------------------
__global__ void wt_kernel(const float* __restrict__ Wq, const float* __restrict__ Wk,
                          const float* __restrict__ Wv, short* __restrict__ wt_base) {
    __shared__ float t[32][33];
    const float* W = (blockIdx.z == 0) ? Wq : (blockIdx.z == 1 ? Wk : Wv);
    short* WT = wt_base + (size_t)blockIdx.z * DM * DM;
    int kb = blockIdx.x * 32, nb = blockIdx.y * 32;
    int tx = threadIdx.x, ty = threadIdx.y;  // 32 x 8
#pragma unroll
    for (int r = 0; r < 4; r++)
        t[ty + 8 * r][tx] = W[(size_t)(kb + ty + 8 * r) * DM + nb + tx];
    __syncthreads();
#pragma unroll
    for (int r = 0; r < 4; r++)
        WT[(size_t)(nb + ty + 8 * r) * DM + kb + tx] = f2bf(t[tx][ty + 8 * r]);
}

// ---------------------------------------------------------------------------
// Kernel 2: fused projections (z = 0:Q, 1:K, 2:V).
// Tile 128x128, BK=32, double-buffered LDS, ONE barrier/iter.
// R2 lesson: the A fp32->reg->convert->ds_write round-trip was the critical
// path. Now BOTH operands stage via async global_load_lds (fire-and-forget,
// drained by the barrier): A staged as RAW FP32 (16KB/buf), converted to bf16
// at fragment-read time (2x ds_read_b128 + 4 pk2bf, in-register).
// Bank conflicts: fp32 128B rows would be 16-way, so XOR-chunk swizzle
// (rule 21: linear LDS dest + inverse-swizzled GLOBAL source + swizzled read;
// XOR is an involution): A chunk^=(row&7) -> 2-way; B chunk^=(row&3).
// LDS 48KB -> 3 blocks/CU. launch_bounds(256,3) (R2: asking 5 squeezed VGPR
// to 48 and regressed; occupancy never rose).
// z<2: out head-major [b][h][s][64].  z==2: out transposed [b][h][64][S].
// Grid 1D (1536) chunked XCD swizzle (R1: FETCH 396->67MB).
// ---------------------------------------------------------------------------
__global__ __launch_bounds__(256, 3) void projf_kernel(
        const float* __restrict__ Xq, const float* __restrict__ Xk,
        const float* __restrict__ Xv, const short* __restrict__ WT3,
        const float* __restrict__ bq, const float* __restrict__ bk,
        const float* __restrict__ bv,
        short* __restrict__ Qh, short* __restrict__ Kh, short* __restrict__ Vt,
        float qscale) {
    __shared__ __align__(16) float Asf[2][128 * 32];  // fp32 A tile, 16KB/buf
    __shared__ __align__(16) short Bs[2][128 * 32];   // bf16 B tile,  8KB/buf
    // ---- chunked bijective XCD swizzle: 1536 = 8 XCDs x 192 ----
    const int bid = blockIdx.x;
    const int swz = (bid & 7) * 192 + (bid >> 3);
    const int nx = swz & 7;          // n-tile (fastest in logical order)
    const int my = (swz >> 3) & 63;  // m-tile
    const int z  = swz >> 9;         // matrix select (8*64 = 512 per z)

    const float* X = (z == 0) ? Xq : (z == 1) ? Xk : Xv;
    const short* WT = WT3 + (size_t)z * DM * DM;
    const float* bias = (z == 0) ? bq : (z == 1) ? bk : bv;
    short* out = (z == 0) ? Qh : (z == 1) ? Kh : Vt;
    const float scale = (z == 0) ? qscale : 1.0f;
    const int mode = (z == 2);

    const int tid = threadIdx.x;
    const int lane = tid & 63, w = tid >> 6;
    const int l15 = lane & 15, quad = lane >> 4;
    const int n0 = nx * 128, m0 = my * 128;
    const int wm = (w & 1) * 64, wn = (w >> 1) * 64;

    const float* xb = X + (size_t)m0 * DM;

    f32x4 acc[4][4];
#pragma unroll
    for (int i = 0; i < 4; i++)
#pragma unroll
        for (int j = 0; j < 4; j++) { acc[i][j][0] = 0.f; acc[i][j][1] = 0.f; acc[i][j][2] = 0.f; acc[i][j][3] = 0.f; }

    // A: 128 rows x 8 chunks(16B) = 1024 slots; global chunk = chunk^(row&7)
    auto stageA = [&](int k0, int bi) {
#pragma unroll
        for (int it = 0; it < 4; it++) {
            int c = it * 256 + tid;
            int row = c >> 3, ch = c & 7;
            int gch = ch ^ (row & 7);
            gload_lds16(xb + (size_t)row * DM + k0 + gch * 4, Asf[bi] + c * 4);
        }
    };
    // B: 128 rows x 4 chunks(16B) = 512 slots; global chunk = chunk^(row&3)
    auto stageB = [&](int k0, int bi) {
#pragma unroll
        for (int it = 0; it < 2; it++) {
            int c = it * 256 + tid;
            int row = c >> 2, ch = c & 3;
            int gch = ch ^ (row & 3);
            gload_lds16(WT + (size_t)(n0 + row) * DM + k0 + gch * 8, Bs[bi] + c * 8);
        }
    };

    // ---- prologue: stage tile 0 into buf 0 ----
    stageA(0, 0);
    stageB(0, 0);

    for (int t = 0; t < 32; t++) {
        const int bi = t & 1;
        __syncthreads();                // tile t staged (vmcnt drained); buf^1 free
        if (t < 31) {                   // issue next tile's async loads NOW
            stageA(t * 32 + 32, bi ^ 1);
            stageB(t * 32 + 32, bi ^ 1);
        }

        short8 af[4], bf[4];
#pragma unroll
        for (int i = 0; i < 4; i++) {   // A frag: fp32 read (swizzled) + convert
            int row = wm + i * 16 + l15;
            int c0 = (quad * 2) ^ (row & 7);
            int c1 = (quad * 2 + 1) ^ (row & 7);
            f32x4 lo = *(const f32x4*)(Asf[bi] + row * 32 + c0 * 4);
            f32x4 hi = *(const f32x4*)(Asf[bi] + row * 32 + c1 * 4);
            uint4 u;
            u.x = pk2bf(lo[0], lo[1]); u.y = pk2bf(lo[2], lo[3]);
            u.z = pk2bf(hi[0], hi[1]); u.w = pk2bf(hi[2], hi[3]);
            af[i] = *(short8*)&u;
        }
#pragma unroll
        for (int j = 0; j < 4; j++) {   // B frag: bf16 read (swizzled)
            int row = wn + j * 16 + l15;
            int cc = quad ^ (row & 3);
            bf[j] = *(const short8*)(Bs[bi] + row * 32 + cc * 8);
        }

#pragma unroll
        for (int i = 0; i < 4; i++)
#pragma unroll
            for (int j = 0; j < 4; j++)
                acc[i][j] = __builtin_amdgcn_mfma_f32_16x16x32_bf16(af[i], bf[j], acc[i][j], 0, 0, 0);
    }

    // ---- epilogue ----
#pragma unroll
    for (int j = 0; j < 4; j++) {
        int col = n0 + wn + j * 16 + l15;
        float bv_ = bias[col];
        int h = col >> 6, d = col & 63;
#pragma unroll
        for (int i = 0; i < 4; i++) {
            int rowbase = m0 + wm + i * 16 + quad * 4;
            int bb = rowbase >> 11, s0 = rowbase & 2047;
            if (mode == 0) {
#pragma unroll
                for (int r = 0; r < 4; r++)
                    out[((size_t)(bb * NH + h) * S_LEN + (s0 + r)) * HD + d] =
                        f2bf((acc[i][j][r] + bv_) * scale);
            } else {
                short4v pk;
#pragma unroll
                for (int r = 0; r < 4; r++) pk[r] = f2bf((acc[i][j][r] + bv_) * scale);
                *(short4v*)(out + ((size_t)(bb * NH + h) * HD + d) * S_LEN + s0) = pk;
            }
        }
    }
}

// ---------------------------------------------------------------------------
// Kernel 3: attention. Block = 256 thr (4 waves), q-tile 128 (wave: 2x16 rows).
// K/V tiles (64 keys) staged block-cooperatively via global_load_lds into
// double-buffered LDS ([half][row][32] 64B rows, m97 bank pattern); tile t+1
// issued at iter start, ONE __syncthreads per iter drains it ~a full body later.
// No-max softmax (Q pre-scaled by 0.125*log2e, exp2); P via wave-private LDS.
// Grid 1D (1024) chunked XCD swizzle: 16 q-tile siblings of one head's K/V
// are consecutive on the same XCD.
// ---------------------------------------------------------------------------
__global__ __launch_bounds__(256, 3) void attn_kernel(
        const short* __restrict__ Q, const short* __restrict__ K,
        const short* __restrict__ V, float* __restrict__ out) {
    __shared__ __align__(16) short Ks[2][2][64][32];  // [buf][half][key-row][32] 16KB
    __shared__ __align__(16) short Vs[2][2][64][32];  // [buf][half][d-row][32]   16KB
    __shared__ __align__(16) short ps[4][2][16 * 72]; // [wave][strip]            18KB
    // ---- chunked bijective XCD swizzle: 1024 = 8 XCDs x 128 ----
    const int bid = blockIdx.x;
    const int swz = (bid & 7) * 128 + (bid >> 3);
    const int qi = swz & 15;         // q-tile (fastest in logical order)
    const int h  = (swz >> 4) & 15;  // head
    const int b  = swz >> 8;         // batch (16*16 = 256 per b)

    const int tid = threadIdx.x;
    const int lane = tid & 63, w = tid >> 6;
    const int l15 = lane & 15, quad = lane >> 4;
    const int q0 = qi * 128;
    const size_t bh = (size_t)(b * NH + h);
    const short* qp = Q + bh * S_LEN * HD;
    const short* kp = K + bh * S_LEN * HD;
    const short* vp = V + bh * (size_t)HD * S_LEN;

    short8 qa[2][2];
#pragma unroll
    for (int s = 0; s < 2; s++) {
        const short* qr = qp + (size_t)(q0 + w * 32 + s * 16 + l15) * HD + quad * 8;
        qa[s][0] = *(const short8*)(qr);
        qa[s][1] = *(const short8*)(qr + 32);
    }

    f32x4 o[2][4];
    float lsum[2][4];
#pragma unroll
    for (int s = 0; s < 2; s++)
#pragma unroll
        for (int d = 0; d < 4; d++) {
            o[s][d][0] = 0.f; o[s][d][1] = 0.f; o[s][d][2] = 0.f; o[s][d][3] = 0.f;
            lsum[s][d] = 0.f;
        }

    auto stageKV = [&](int kt, int bi) {
        short* kd = &Ks[bi][0][0][0];
        short* vd = &Vs[bi][0][0][0];
#pragma unroll
        for (int it = 0; it < 2; it++) {
            int c = it * 256 + tid;                  // 512 slots x 16B = 8KB each
            int half = c >> 8, row = (c >> 2) & 63, chunk = c & 3;
            int co = half * 32 + chunk * 8;
            gload_lds16(kp + (size_t)(kt + row) * HD + co, kd + c * 8);
            gload_lds16(vp + (size_t)row * S_LEN + kt + co, vd + c * 8);
        }
    };

    stageKV(0, 0);

    for (int t = 0; t < 32; t++) {
        const int bi = t & 1;
        __syncthreads();                 // tile t ready (vmcnt drained); buf^1 free
        if (t < 31) stageKV((t + 1) << 6, bi ^ 1);   // issue next tile NOW

        // ---- K frags from LDS (shared by both strips) + QK^T ----
        short8 kf[4][2];
#pragma unroll
        for (int nb = 0; nb < 4; nb++) {
            kf[nb][0] = *(const short8*)(&Ks[bi][0][nb * 16 + l15][quad * 8]);
            kf[nb][1] = *(const short8*)(&Ks[bi][1][nb * 16 + l15][quad * 8]);
        }
        f32x4 sacc[2][4];
#pragma unroll
        for (int nb = 0; nb < 4; nb++)
#pragma unroll
            for (int s = 0; s < 2; s++) {
                f32x4 zz; zz[0] = 0.f; zz[1] = 0.f; zz[2] = 0.f; zz[3] = 0.f;
                zz = __builtin_amdgcn_mfma_f32_16x16x32_bf16(qa[s][0], kf[nb][0], zz, 0, 0, 0);
                sacc[s][nb] = __builtin_amdgcn_mfma_f32_16x16x32_bf16(qa[s][1], kf[nb][1], zz, 0, 0, 0);
            }
        // ---- P = exp2(S'); partial row-sums; P -> wave-private LDS ----
#pragma unroll
        for (int s = 0; s < 2; s++)
#pragma unroll
            for (int r = 0; r < 4; r++)
#pragma unroll
                for (int nb = 0; nb < 4; nb++) {
                    float p = fexp2(sacc[s][nb][r]);
                    lsum[s][r] += p;
                    ps[w][s][(quad * 4 + r) * 72 + nb * 16 + l15] = f2bf_ru(p);
                }
        asm volatile("s_waitcnt lgkmcnt(0)" ::: "memory");
        short8 pa[2][2];
#pragma unroll
        for (int s = 0; s < 2; s++) {
            pa[s][0] = *(const short8*)(&ps[w][s][l15 * 72 + quad * 8]);
            pa[s][1] = *(const short8*)(&ps[w][s][l15 * 72 + 32 + quad * 8]);
        }
        // ---- V frags from LDS + PV ----
#pragma unroll
        for (int dd = 0; dd < 4; dd++) {
            short8 v0 = *(const short8*)(&Vs[bi][0][dd * 16 + l15][quad * 8]);
            short8 v1 = *(const short8*)(&Vs[bi][1][dd * 16 + l15][quad * 8]);
#pragma unroll
            for (int s = 0; s < 2; s++) {
                o[s][dd] = __builtin_amdgcn_mfma_f32_16x16x32_bf16(pa[s][0], v0, o[s][dd], 0, 0, 0);
                o[s][dd] = __builtin_amdgcn_mfma_f32_16x16x32_bf16(pa[s][1], v1, o[s][dd], 0, 0, 0);
            }
        }
    }

    // ---- deferred l reduction + epilogue ----
#pragma unroll
    for (int s = 0; s < 2; s++) {
#pragma unroll
        for (int r = 0; r < 4; r++) {
            float l = lsum[s][r];
            l += __shfl_xor(l, 1);
            l += __shfl_xor(l, 2);
            l += __shfl_xor(l, 4);
            l += __shfl_xor(l, 8);
            lsum[s][r] = 1.f / l;
        }
        float* orow = out + ((size_t)b * S_LEN + q0 + w * 32 + s * 16 + quad * 4) * DM + h * HD + l15;
#pragma unroll
        for (int r = 0; r < 4; r++)
#pragma unroll
            for (int dd = 0; dd < 4; dd++)
                orow[(size_t)r * DM + dd * 16] = o[s][dd][r] * lsum[s][r];
    }
}

// ---------------------------------------------------------------------------
// ws (56.6 MB): [0,6.3M) WT x3 bf16 | Qh | Kh | Vt (16.8M each)
// ---------------------------------------------------------------------------
extern "C" void kernel_launch(void* const* d_in, const int* in_sizes, int n_in,
                              void* d_out, int out_size, void* d_ws, size_t ws_size,
                              hipStream_t stream) {
    const float* query  = (const float*)d_in[0];
    const float* key_in = (const float*)d_in[1];
    const float* value  = (const float*)d_in[2];
    const float* Wq = (const float*)d_in[3];
    const float* bq = (const float*)d_in[4];
    const float* Wk = (const float*)d_in[5];
    const float* bk = (const float*)d_in[6];
    const float* Wv = (const float*)d_in[7];
    const float* bv = (const float*)d_in[8];

    short* wt = (short*)d_ws;
    short* Qh = wt + 3 * 1048576;
    short* Kh = Qh + 8388608;
    short* Vt = Kh + 8388608;
    float* out = (float*)d_out;

    const float QSCALE = 0.125f * 1.44269504088896340736f;  // 1/sqrt(64) * log2(e)

    wt_kernel<<<dim3(32, 32, 3), dim3(32, 8), 0, stream>>>(Wq, Wk, Wv, wt);
    projf_kernel<<<dim3(1536), 256, 0, stream>>>(query, key_in, value, wt,
                                                 bq, bk, bv, Qh, Kh, Vt, QSCALE);
    attn_kernel<<<dim3(1024), 256, 0, stream>>>(Qh, Kh, Vt, out);
}

// Round 4
// 348.951 us; speedup vs baseline: 1.2866x; 1.0610x over previous
//
#include <hip/hip_runtime.h>
#include <hip/hip_bf16.h>

// B=4, S=2048, D_MODEL=1024, H=16, HEAD=64. Inputs fp32, output fp32.
#define S_LEN 2048
#define DM    1024
#define NH    16
#define HD    64

typedef __attribute__((ext_vector_type(8))) short short8;   // 8 bf16 (MFMA A/B frag)
typedef __attribute__((ext_vector_type(4))) short short4v;  // 4 bf16 (8B store)
typedef __attribute__((ext_vector_type(4))) float f32x4;    // MFMA C/D frag

// fp32 -> bf16 RNE (weight/output paths)
__device__ __forceinline__ short f2bf(float f) {
    union { float f; unsigned u; } x; x.f = f;
    unsigned u = x.u;
    return (short)((u + 0x7FFFu + ((u >> 16) & 1u)) >> 16);
}
// round-half-up variants (2 VALU; bias negligible for continuous data)
__device__ __forceinline__ short f2bf_ru(float f) {
    return (short)((__float_as_uint(f) + 0x8000u) >> 16);
}
__device__ __forceinline__ unsigned pk2bf(float a, float b) {
    unsigned ua = __float_as_uint(a) + 0x8000u;
    unsigned ub = __float_as_uint(b) + 0x8000u;
    return (ua >> 16) | (ub & 0xFFFF0000u);
}
__device__ __forceinline__ float fexp2(float x) {
#if __has_builtin(__builtin_amdgcn_exp2f)
    return __builtin_amdgcn_exp2f(x);
#else
    return exp2f(x);
#endif
}
// async global->LDS, 16B per lane (wave-uniform base + lane*16 dest)
__device__ __forceinline__ void gload_lds16(const void* g, void* l) {
    __builtin_amdgcn_global_load_lds(
        (const __attribute__((address_space(1))) unsigned int*)g,
        (__attribute__((address_space(3))) unsigned int*)l, 16, 0, 0);
}

// ---------------------------------------------------------------------------
// Kernel 1: W [K][N] fp32 -> WT [N][K] bf16 for Wq/Wk/Wv (blockIdx.z)
// ---------------------------------------------------------------------------
__global__ void wt_kernel(const float* __restrict__ Wq, const float* __restrict__ Wk,
                          const float* __restrict__ Wv, short* __restrict__ wt_base) {
    __shared__ float t[32][33];
    const float* W = (blockIdx.z == 0) ? Wq : (blockIdx.z == 1 ? Wk : Wv);
    short* WT = wt_base + (size_t)blockIdx.z * DM * DM;
    int kb = blockIdx.x * 32, nb = blockIdx.y * 32;
    int tx = threadIdx.x, ty = threadIdx.y;  // 32 x 8
#pragma unroll
    for (int r = 0; r < 4; r++)
        t[ty + 8 * r][tx] = W[(size_t)(kb + ty + 8 * r) * DM + nb + tx];
    __syncthreads();
#pragma unroll
    for (int r = 0; r < 4; r++)
        WT[(size_t)(nb + ty + 8 * r) * DM + kb + tx] = f2bf(t[tx][ty + 8 * r]);
}

// ---------------------------------------------------------------------------
// Kernel 2: fused projections (z = 0:Q, 1:K, 2:V).
// R1/R3 lesson: A-staging method and HBM traffic both ~irrelevant -> the
// limiter is per-iter slot overhead at only 12 waves/CU + 2-round dispatch.
// This round: 512-thread blocks, tile 128(M) x 256(N), BK=32. Each of the
// 8 waves keeps the EXACT m97 per-wave body (64x64 out, 8 ds_read_b128,
// 16 MFMA, acc[4][4]) -- only block-level sharing changed.
//   - LDS 48KB (A 8K + B 16K, x2 buf) -> 3 blocks/CU = 24 waves/CU (6/SIMD),
//     2x the TLP of the 256-thr version.
//   - Grid 768 blocks = exactly 3/CU x 256 CU: ONE dispatch round, no tail.
//   - A: reg-staged bf16 (2 float4 + 4 pk2bf + 1 ds_write_b128 per thread);
//     B: async global_load_lds. One barrier/iter, R1-proven ordering.
// z<2: out head-major [b][h][s][64].  z==2: out transposed [b][h][64][S].
// Grid 1D chunked XCD swizzle: 768 = 8 XCDs x 96 (4 n-tiles/panel share X).
// ---------------------------------------------------------------------------
__global__ __launch_bounds__(512, 2) void projf_kernel(
        const float* __restrict__ Xq, const float* __restrict__ Xk,
        const float* __restrict__ Xv, const short* __restrict__ WT3,
        const float* __restrict__ bq, const float* __restrict__ bk,
        const float* __restrict__ bv,
        short* __restrict__ Qh, short* __restrict__ Kh, short* __restrict__ Vt,
        float qscale) {
    __shared__ __align__(16) short As[2][128 * 32];   // bf16 A tile,  8KB/buf
    __shared__ __align__(16) short Bs[2][256 * 32];   // bf16 B tile, 16KB/buf
    // ---- chunked bijective XCD swizzle: 768 = 8 XCDs x 96 ----
    const int bid = blockIdx.x;
    const int swz = (bid & 7) * 96 + (bid >> 3);
    const int nx = swz & 3;          // n-tile (fastest logical: 4 share X panel)
    const int my = (swz >> 2) & 63;  // m-tile
    const int z  = swz >> 8;         // matrix select (4*64 = 256 per z)

    const float* X = (z == 0) ? Xq : (z == 1) ? Xk : Xv;
    const short* WT = WT3 + (size_t)z * DM * DM;
    const float* bias = (z == 0) ? bq : (z == 1) ? bk : bv;
    short* out = (z == 0) ? Qh : (z == 1) ? Kh : Vt;
    const float scale = (z == 0) ? qscale : 1.0f;
    const int mode = (z == 2);

    const int tid = threadIdx.x;
    const int lane = tid & 63, w = tid >> 6;          // 8 waves
    const int l15 = lane & 15, quad = lane >> 4;
    const int n0 = nx * 256, m0 = my * 128;
    const int wm = (w & 1) * 64, wn = (w >> 1) * 64;  // 2M x 4N wave grid
    const int arow = tid >> 2;          // A staging: 4 threads/row
    const int ako  = (tid & 3) * 8;     // 8 floats (=8 bf16 out) per thread

    const float* xb = X + (size_t)m0 * DM;

    f32x4 acc[4][4];
#pragma unroll
    for (int i = 0; i < 4; i++)
#pragma unroll
        for (int j = 0; j < 4; j++) { acc[i][j][0] = 0.f; acc[i][j][1] = 0.f; acc[i][j][2] = 0.f; acc[i][j][3] = 0.f; }

    // B: 256 rows x 4 chunks(16B) = 1024 slots, 2 insts/thread
    auto stageB = [&](int k0, int bi) {
#pragma unroll
        for (int it = 0; it < 2; it++) {
            int c = it * 512 + tid;
            int row = c >> 2, ko = (c & 3) * 8;
            gload_lds16(WT + (size_t)(n0 + row) * DM + k0 + ko, Bs[bi] + c * 8);
        }
    };

    // ---- prologue: stage tile 0 into buf 0 ----
    float4 a0, a1;
    a0 = *(const float4*)(xb + (size_t)arow * DM + ako);
    a1 = *(const float4*)(xb + (size_t)arow * DM + ako + 4);
    stageB(0, 0);
    {
        uint4 p;
        p.x = pk2bf(a0.x, a0.y); p.y = pk2bf(a0.z, a0.w);
        p.z = pk2bf(a1.x, a1.y); p.w = pk2bf(a1.z, a1.w);
        *(uint4*)(As[0] + arow * 32 + ako) = p;
    }

    for (int t = 0; t < 32; t++) {
        const int bi = t & 1;
        const int kn = t * 32 + 32;     // next tile's k0
        __syncthreads();                // tile t staged (vmcnt+lgkm drained)

        short8 af[4], bf[4];
#pragma unroll
        for (int i = 0; i < 4; i++)
            af[i] = *(const short8*)(As[bi] + (wm + i * 16 + l15) * 32 + quad * 8);
#pragma unroll
        for (int j = 0; j < 4; j++)
            bf[j] = *(const short8*)(Bs[bi] + (wn + j * 16 + l15) * 32 + quad * 8);

        if (t < 31) {                   // issue next tile's loads
            a0 = *(const float4*)(xb + (size_t)arow * DM + kn + ako);
            a1 = *(const float4*)(xb + (size_t)arow * DM + kn + ako + 4);
            stageB(kn, bi ^ 1);
        }

#pragma unroll
        for (int i = 0; i < 4; i++)
#pragma unroll
            for (int j = 0; j < 4; j++)
                acc[i][j] = __builtin_amdgcn_mfma_f32_16x16x32_bf16(af[i], bf[j], acc[i][j], 0, 0, 0);

        if (t < 31) {                   // convert+write A for tile t+1
            uint4 p;
            p.x = pk2bf(a0.x, a0.y); p.y = pk2bf(a0.z, a0.w);
            p.z = pk2bf(a1.x, a1.y); p.w = pk2bf(a1.z, a1.w);
            *(uint4*)(As[bi ^ 1] + arow * 32 + ako) = p;
        }
    }

    // ---- epilogue ----
#pragma unroll
    for (int j = 0; j < 4; j++) {
        int col = n0 + wn + j * 16 + l15;
        float bv_ = bias[col];
        int h = col >> 6, d = col & 63;
#pragma unroll
        for (int i = 0; i < 4; i++) {
            int rowbase = m0 + wm + i * 16 + quad * 4;
            int bb = rowbase >> 11, s0 = rowbase & 2047;
            if (mode == 0) {
#pragma unroll
                for (int r = 0; r < 4; r++)
                    out[((size_t)(bb * NH + h) * S_LEN + (s0 + r)) * HD + d] =
                        f2bf((acc[i][j][r] + bv_) * scale);
            } else {
                short4v pk;
#pragma unroll
                for (int r = 0; r < 4; r++) pk[r] = f2bf((acc[i][j][r] + bv_) * scale);
                *(short4v*)(out + ((size_t)(bb * NH + h) * HD + d) * S_LEN + s0) = pk;
            }
        }
    }
}

// ---------------------------------------------------------------------------
// Kernel 3: attention. Block = 256 thr (4 waves), q-tile 128 (wave: 2x16 rows).
// K/V tiles (64 keys) staged block-cooperatively via global_load_lds into
// double-buffered LDS ([half][row][32] 64B rows, m97 bank pattern); tile t+1
// issued at iter start, ONE __syncthreads per iter drains it ~a full body later.
// No-max softmax (Q pre-scaled by 0.125*log2e, exp2); P via wave-private LDS.
// Grid 1D (1024) chunked XCD swizzle: 16 q-tile siblings of one head's K/V
// are consecutive on the same XCD.
// ---------------------------------------------------------------------------
__global__ __launch_bounds__(256, 3) void attn_kernel(
        const short* __restrict__ Q, const short* __restrict__ K,
        const short* __restrict__ V, float* __restrict__ out) {
    __shared__ __align__(16) short Ks[2][2][64][32];  // [buf][half][key-row][32] 16KB
    __shared__ __align__(16) short Vs[2][2][64][32];  // [buf][half][d-row][32]   16KB
    __shared__ __align__(16) short ps[4][2][16 * 72]; // [wave][strip]            18KB
    // ---- chunked bijective XCD swizzle: 1024 = 8 XCDs x 128 ----
    const int bid = blockIdx.x;
    const int swz = (bid & 7) * 128 + (bid >> 3);
    const int qi = swz & 15;         // q-tile (fastest in logical order)
    const int h  = (swz >> 4) & 15;  // head
    const int b  = swz >> 8;         // batch (16*16 = 256 per b)

    const int tid = threadIdx.x;
    const int lane = tid & 63, w = tid >> 6;
    const int l15 = lane & 15, quad = lane >> 4;
    const int q0 = qi * 128;
    const size_t bh = (size_t)(b * NH + h);
    const short* qp = Q + bh * S_LEN * HD;
    const short* kp = K + bh * S_LEN * HD;
    const short* vp = V + bh * (size_t)HD * S_LEN;

    short8 qa[2][2];
#pragma unroll
    for (int s = 0; s < 2; s++) {
        const short* qr = qp + (size_t)(q0 + w * 32 + s * 16 + l15) * HD + quad * 8;
        qa[s][0] = *(const short8*)(qr);
        qa[s][1] = *(const short8*)(qr + 32);
    }

    f32x4 o[2][4];
    float lsum[2][4];
#pragma unroll
    for (int s = 0; s < 2; s++)
#pragma unroll
        for (int d = 0; d < 4; d++) {
            o[s][d][0] = 0.f; o[s][d][1] = 0.f; o[s][d][2] = 0.f; o[s][d][3] = 0.f;
            lsum[s][d] = 0.f;
        }

    auto stageKV = [&](int kt, int bi) {
        short* kd = &Ks[bi][0][0][0];
        short* vd = &Vs[bi][0][0][0];
#pragma unroll
        for (int it = 0; it < 2; it++) {
            int c = it * 256 + tid;                  // 512 slots x 16B = 8KB each
            int half = c >> 8, row = (c >> 2) & 63, chunk = c & 3;
            int co = half * 32 + chunk * 8;
            gload_lds16(kp + (size_t)(kt + row) * HD + co, kd + c * 8);
            gload_lds16(vp + (size_t)row * S_LEN + kt + co, vd + c * 8);
        }
    };

    stageKV(0, 0);

    for (int t = 0; t < 32; t++) {
        const int bi = t & 1;
        __syncthreads();                 // tile t ready (vmcnt drained); buf^1 free
        if (t < 31) stageKV((t + 1) << 6, bi ^ 1);   // issue next tile NOW

        // ---- K frags from LDS (shared by both strips) + QK^T ----
        short8 kf[4][2];
#pragma unroll
        for (int nb = 0; nb < 4; nb++) {
            kf[nb][0] = *(const short8*)(&Ks[bi][0][nb * 16 + l15][quad * 8]);
            kf[nb][1] = *(const short8*)(&Ks[bi][1][nb * 16 + l15][quad * 8]);
        }
        f32x4 sacc[2][4];
#pragma unroll
        for (int nb = 0; nb < 4; nb++)
#pragma unroll
            for (int s = 0; s < 2; s++) {
                f32x4 zz; zz[0] = 0.f; zz[1] = 0.f; zz[2] = 0.f; zz[3] = 0.f;
                zz = __builtin_amdgcn_mfma_f32_16x16x32_bf16(qa[s][0], kf[nb][0], zz, 0, 0, 0);
                sacc[s][nb] = __builtin_amdgcn_mfma_f32_16x16x32_bf16(qa[s][1], kf[nb][1], zz, 0, 0, 0);
            }
        // ---- P = exp2(S'); partial row-sums; P -> wave-private LDS ----
#pragma unroll
        for (int s = 0; s < 2; s++)
#pragma unroll
            for (int r = 0; r < 4; r++)
#pragma unroll
                for (int nb = 0; nb < 4; nb++) {
                    float p = fexp2(sacc[s][nb][r]);
                    lsum[s][r] += p;
                    ps[w][s][(quad * 4 + r) * 72 + nb * 16 + l15] = f2bf_ru(p);
                }
        asm volatile("s_waitcnt lgkmcnt(0)" ::: "memory");
        short8 pa[2][2];
#pragma unroll
        for (int s = 0; s < 2; s++) {
            pa[s][0] = *(const short8*)(&ps[w][s][l15 * 72 + quad * 8]);
            pa[s][1] = *(const short8*)(&ps[w][s][l15 * 72 + 32 + quad * 8]);
        }
        // ---- V frags from LDS + PV ----
#pragma unroll
        for (int dd = 0; dd < 4; dd++) {
            short8 v0 = *(const short8*)(&Vs[bi][0][dd * 16 + l15][quad * 8]);
            short8 v1 = *(const short8*)(&Vs[bi][1][dd * 16 + l15][quad * 8]);
#pragma unroll
            for (int s = 0; s < 2; s++) {
                o[s][dd] = __builtin_amdgcn_mfma_f32_16x16x32_bf16(pa[s][0], v0, o[s][dd], 0, 0, 0);
                o[s][dd] = __builtin_amdgcn_mfma_f32_16x16x32_bf16(pa[s][1], v1, o[s][dd], 0, 0, 0);
            }
        }
    }

    // ---- deferred l reduction + epilogue ----
#pragma unroll
    for (int s = 0; s < 2; s++) {
#pragma unroll
        for (int r = 0; r < 4; r++) {
            float l = lsum[s][r];
            l += __shfl_xor(l, 1);
            l += __shfl_xor(l, 2);
            l += __shfl_xor(l, 4);
            l += __shfl_xor(l, 8);
            lsum[s][r] = 1.f / l;
        }
        float* orow = out + ((size_t)b * S_LEN + q0 + w * 32 + s * 16 + quad * 4) * DM + h * HD + l15;
#pragma unroll
        for (int r = 0; r < 4; r++)
#pragma unroll
            for (int dd = 0; dd < 4; dd++)
                orow[(size_t)r * DM + dd * 16] = o[s][dd][r] * lsum[s][r];
    }
}

// ---------------------------------------------------------------------------
// ws (56.6 MB): [0,6.3M) WT x3 bf16 | Qh | Kh | Vt (16.8M each)
// ---------------------------------------------------------------------------
extern "C" void kernel_launch(void* const* d_in, const int* in_sizes, int n_in,
                              void* d_out, int out_size, void* d_ws, size_t ws_size,
                              hipStream_t stream) {
    const float* query  = (const float*)d_in[0];
    const float* key_in = (const float*)d_in[1];
    const float* value  = (const float*)d_in[2];
    const float* Wq = (const float*)d_in[3];
    const float* bq = (const float*)d_in[4];
    const float* Wk = (const float*)d_in[5];
    const float* bk = (const float*)d_in[6];
    const float* Wv = (const float*)d_in[7];
    const float* bv = (const float*)d_in[8];

    short* wt = (short*)d_ws;
    short* Qh = wt + 3 * 1048576;
    short* Kh = Qh + 8388608;
    short* Vt = Kh + 8388608;
    float* out = (float*)d_out;

    const float QSCALE = 0.125f * 1.44269504088896340736f;  // 1/sqrt(64) * log2(e)

    wt_kernel<<<dim3(32, 32, 3), dim3(32, 8), 0, stream>>>(Wq, Wk, Wv, wt);
    projf_kernel<<<dim3(768), 512, 0, stream>>>(query, key_in, value, wt,
                                                bq, bk, bv, Qh, Kh, Vt, QSCALE);
    attn_kernel<<<dim3(1024), 256, 0, stream>>>(Qh, Kh, Vt, out);
}

// Round 5
// 319.746 us; speedup vs baseline: 1.4041x; 1.0913x over previous
//
#include <hip/hip_runtime.h>
#include <hip/hip_bf16.h>

// B=4, S=2048, D_MODEL=1024, H=16, HEAD=64. Inputs fp32, output fp32.
#define S_LEN 2048
#define DM    1024
#define NH    16
#define HD    64

typedef __attribute__((ext_vector_type(8))) short short8;   // 8 bf16 (MFMA A/B frag)
typedef __attribute__((ext_vector_type(4))) short short4v;  // 4 bf16 (8B store)
typedef __attribute__((ext_vector_type(4))) float f32x4;    // MFMA C/D frag

// fp32 -> bf16 RNE (weight/output paths)
__device__ __forceinline__ short f2bf(float f) {
    union { float f; unsigned u; } x; x.f = f;
    unsigned u = x.u;
    return (short)((u + 0x7FFFu + ((u >> 16) & 1u)) >> 16);
}
// round-half-up variants (2 VALU; bias negligible for continuous data)
__device__ __forceinline__ short f2bf_ru(float f) {
    return (short)((__float_as_uint(f) + 0x8000u) >> 16);
}
__device__ __forceinline__ unsigned pk2bf(float a, float b) {
    unsigned ua = __float_as_uint(a) + 0x8000u;
    unsigned ub = __float_as_uint(b) + 0x8000u;
    return (ua >> 16) | (ub & 0xFFFF0000u);
}
__device__ __forceinline__ float fexp2(float x) {
#if __has_builtin(__builtin_amdgcn_exp2f)
    return __builtin_amdgcn_exp2f(x);
#else
    return exp2f(x);
#endif
}
// async global->LDS, 16B per lane (wave-uniform base + lane*16 dest)
__device__ __forceinline__ void gload_lds16(const void* g, void* l) {
    __builtin_amdgcn_global_load_lds(
        (const __attribute__((address_space(1))) unsigned int*)g,
        (__attribute__((address_space(3))) unsigned int*)l, 16, 0, 0);
}

// ---------------------------------------------------------------------------
// Kernel 1: W [K][N] fp32 -> WT [N][K] bf16 for Wq/Wk/Wv (blockIdx.z)
// ---------------------------------------------------------------------------
__global__ void wt_kernel(const float* __restrict__ Wq, const float* __restrict__ Wk,
                          const float* __restrict__ Wv, short* __restrict__ wt_base) {
    __shared__ float t[32][33];
    const float* W = (blockIdx.z == 0) ? Wq : (blockIdx.z == 1 ? Wk : Wv);
    short* WT = wt_base + (size_t)blockIdx.z * DM * DM;
    int kb = blockIdx.x * 32, nb = blockIdx.y * 32;
    int tx = threadIdx.x, ty = threadIdx.y;  // 32 x 8
#pragma unroll
    for (int r = 0; r < 4; r++)
        t[ty + 8 * r][tx] = W[(size_t)(kb + ty + 8 * r) * DM + nb + tx];
    __syncthreads();
#pragma unroll
    for (int r = 0; r < 4; r++)
        WT[(size_t)(nb + ty + 8 * r) * DM + kb + tx] = f2bf(t[tx][ty + 8 * r]);
}

// ---------------------------------------------------------------------------
// Kernel 2: fused projections (z = 0:Q, 1:K, 2:V).
// 512-thr blocks, tile 128(M) x 256(N), BK=32; each of the 8 waves keeps the
// m97 per-wave body (64x64 out, 8 ds_read_b128, 16 MFMA, acc[4][4]).
// LDS 48KB x2buf -> 3 blocks/CU; grid 768 = one dispatch round, no tail.
// R5: staging (A float4 + B global_load_lds for tile t+1) issued at ITER TOP,
// before frag ds_reads -> A loads get frag-reads + 16 MFMAs (~400-600cy) of
// cover before the end-of-iter convert consumes them (R2's reorder was
// confounded by the VGPR-48 squeeze; retested clean here at VGPR~60).
// z<2: out head-major [b][h][s][64].  z==2: out transposed [b][h][64][S].
// Grid 1D chunked XCD swizzle: 768 = 8 XCDs x 96 (4 n-tiles/panel share X).
// ---------------------------------------------------------------------------
__global__ __launch_bounds__(512, 2) void projf_kernel(
        const float* __restrict__ Xq, const float* __restrict__ Xk,
        const float* __restrict__ Xv, const short* __restrict__ WT3,
        const float* __restrict__ bq, const float* __restrict__ bk,
        const float* __restrict__ bv,
        short* __restrict__ Qh, short* __restrict__ Kh, short* __restrict__ Vt,
        float qscale) {
    __shared__ __align__(16) short As[2][128 * 32];   // bf16 A tile,  8KB/buf
    __shared__ __align__(16) short Bs[2][256 * 32];   // bf16 B tile, 16KB/buf
    // ---- chunked bijective XCD swizzle: 768 = 8 XCDs x 96 ----
    const int bid = blockIdx.x;
    const int swz = (bid & 7) * 96 + (bid >> 3);
    const int nx = swz & 3;          // n-tile (fastest logical: 4 share X panel)
    const int my = (swz >> 2) & 63;  // m-tile
    const int z  = swz >> 8;         // matrix select (4*64 = 256 per z)

    const float* X = (z == 0) ? Xq : (z == 1) ? Xk : Xv;
    const short* WT = WT3 + (size_t)z * DM * DM;
    const float* bias = (z == 0) ? bq : (z == 1) ? bk : bv;
    short* out = (z == 0) ? Qh : (z == 1) ? Kh : Vt;
    const float scale = (z == 0) ? qscale : 1.0f;
    const int mode = (z == 2);

    const int tid = threadIdx.x;
    const int lane = tid & 63, w = tid >> 6;          // 8 waves
    const int l15 = lane & 15, quad = lane >> 4;
    const int n0 = nx * 256, m0 = my * 128;
    const int wm = (w & 1) * 64, wn = (w >> 1) * 64;  // 2M x 4N wave grid
    const int arow = tid >> 2;          // A staging: 4 threads/row
    const int ako  = (tid & 3) * 8;     // 8 floats (=8 bf16 out) per thread

    const float* xb = X + (size_t)m0 * DM;

    f32x4 acc[4][4];
#pragma unroll
    for (int i = 0; i < 4; i++)
#pragma unroll
        for (int j = 0; j < 4; j++) { acc[i][j][0] = 0.f; acc[i][j][1] = 0.f; acc[i][j][2] = 0.f; acc[i][j][3] = 0.f; }

    // B: 256 rows x 4 chunks(16B) = 1024 slots, 2 insts/thread
    auto stageB = [&](int k0, int bi) {
#pragma unroll
        for (int it = 0; it < 2; it++) {
            int c = it * 512 + tid;
            int row = c >> 2, ko = (c & 3) * 8;
            gload_lds16(WT + (size_t)(n0 + row) * DM + k0 + ko, Bs[bi] + c * 8);
        }
    };

    // ---- prologue: stage tile 0 into buf 0 ----
    float4 a0, a1;
    a0 = *(const float4*)(xb + (size_t)arow * DM + ako);
    a1 = *(const float4*)(xb + (size_t)arow * DM + ako + 4);
    stageB(0, 0);
    {
        uint4 p;
        p.x = pk2bf(a0.x, a0.y); p.y = pk2bf(a0.z, a0.w);
        p.z = pk2bf(a1.x, a1.y); p.w = pk2bf(a1.z, a1.w);
        *(uint4*)(As[0] + arow * 32 + ako) = p;
    }

    for (int t = 0; t < 32; t++) {
        const int bi = t & 1;
        const int kn = t * 32 + 32;     // next tile's k0
        __syncthreads();                // tile t staged (vmcnt+lgkm drained)

        if (t < 31) {                   // STAGE AT TOP: max cover before use
            a0 = *(const float4*)(xb + (size_t)arow * DM + kn + ako);
            a1 = *(const float4*)(xb + (size_t)arow * DM + kn + ako + 4);
            stageB(kn, bi ^ 1);
        }

        short8 af[4], bf[4];
#pragma unroll
        for (int i = 0; i < 4; i++)
            af[i] = *(const short8*)(As[bi] + (wm + i * 16 + l15) * 32 + quad * 8);
#pragma unroll
        for (int j = 0; j < 4; j++)
            bf[j] = *(const short8*)(Bs[bi] + (wn + j * 16 + l15) * 32 + quad * 8);

#pragma unroll
        for (int i = 0; i < 4; i++)
#pragma unroll
            for (int j = 0; j < 4; j++)
                acc[i][j] = __builtin_amdgcn_mfma_f32_16x16x32_bf16(af[i], bf[j], acc[i][j], 0, 0, 0);

        if (t < 31) {                   // convert+write A for tile t+1
            uint4 p;
            p.x = pk2bf(a0.x, a0.y); p.y = pk2bf(a0.z, a0.w);
            p.z = pk2bf(a1.x, a1.y); p.w = pk2bf(a1.z, a1.w);
            *(uint4*)(As[bi ^ 1] + arow * 32 + ako) = p;
        }
    }

    // ---- epilogue ----
#pragma unroll
    for (int j = 0; j < 4; j++) {
        int col = n0 + wn + j * 16 + l15;
        float bv_ = bias[col];
        int h = col >> 6, d = col & 63;
#pragma unroll
        for (int i = 0; i < 4; i++) {
            int rowbase = m0 + wm + i * 16 + quad * 4;
            int bb = rowbase >> 11, s0 = rowbase & 2047;
            if (mode == 0) {
#pragma unroll
                for (int r = 0; r < 4; r++)
                    out[((size_t)(bb * NH + h) * S_LEN + (s0 + r)) * HD + d] =
                        f2bf((acc[i][j][r] + bv_) * scale);
            } else {
                short4v pk;
#pragma unroll
                for (int r = 0; r < 4; r++) pk[r] = f2bf((acc[i][j][r] + bv_) * scale);
                *(short4v*)(out + ((size_t)(bb * NH + h) * HD + d) * S_LEN + s0) = pk;
            }
        }
    }
}

// ---------------------------------------------------------------------------
// Kernel 3: attention. R5: 512 thr / 8 waves, q-tile 256 (wave: 2x16 rows).
// Rationale: attn (~190us, hidden from counter table by a join artifact) is
// the DOMINANT dispatch. 8-wave blocks: K/V staging serves 8 waves (2 gload
// insts/thread vs 4), 2x MFMA work per barrier+stage, LDS 68KB -> 2 blocks/CU
// = 16 waves/CU, grid 512 = exactly 2/CU x 256CU: ALL blocks resident, no
// tail (was 1024 blocks = 1.33 ragged rounds).
// Per-wave body unchanged: QK^T (16 MFMA), no-max softmax (Q pre-scaled by
// 0.125*log2e, exp2), P via wave-private LDS, PV (16 MFMA).
// Grid 1D chunked XCD swizzle: 512 = 8 XCDs x 64 (8 q-tile siblings of one
// head's K/V consecutive on the same XCD).
// ---------------------------------------------------------------------------
__global__ __launch_bounds__(512, 2) void attn_kernel(
        const short* __restrict__ Q, const short* __restrict__ K,
        const short* __restrict__ V, float* __restrict__ out) {
    __shared__ __align__(16) short Ks[2][2][64][32];  // [buf][half][key-row][32] 16KB
    __shared__ __align__(16) short Vs[2][2][64][32];  // [buf][half][d-row][32]   16KB
    __shared__ __align__(16) short ps[8][2][16 * 72]; // [wave][strip]            36KB
    // ---- chunked bijective XCD swizzle: 512 = 8 XCDs x 64 ----
    const int bid = blockIdx.x;
    const int swz = (bid & 7) * 64 + (bid >> 3);
    const int qi = swz & 7;          // q-tile (fastest in logical order)
    const int h  = (swz >> 3) & 15;  // head
    const int b  = swz >> 7;         // batch (8*16 = 128 per b)

    const int tid = threadIdx.x;
    const int lane = tid & 63, w = tid >> 6;          // 8 waves
    const int l15 = lane & 15, quad = lane >> 4;
    const int q0 = qi * 256;
    const size_t bh = (size_t)(b * NH + h);
    const short* qp = Q + bh * S_LEN * HD;
    const short* kp = K + bh * S_LEN * HD;
    const short* vp = V + bh * (size_t)HD * S_LEN;

    short8 qa[2][2];
#pragma unroll
    for (int s = 0; s < 2; s++) {
        const short* qr = qp + (size_t)(q0 + w * 32 + s * 16 + l15) * HD + quad * 8;
        qa[s][0] = *(const short8*)(qr);
        qa[s][1] = *(const short8*)(qr + 32);
    }

    f32x4 o[2][4];
    float lsum[2][4];
#pragma unroll
    for (int s = 0; s < 2; s++)
#pragma unroll
        for (int d = 0; d < 4; d++) {
            o[s][d][0] = 0.f; o[s][d][1] = 0.f; o[s][d][2] = 0.f; o[s][d][3] = 0.f;
            lsum[s][d] = 0.f;
        }

    // 512 slots(K) + 512 slots(V), one 16B inst each per thread
    auto stageKV = [&](int kt, int bi) {
        int c = tid;
        int half = c >> 8, row = (c >> 2) & 63, chunk = c & 3;
        int co = half * 32 + chunk * 8;
        gload_lds16(kp + (size_t)(kt + row) * HD + co, &Ks[bi][0][0][0] + c * 8);
        gload_lds16(vp + (size_t)row * S_LEN + kt + co, &Vs[bi][0][0][0] + c * 8);
    };

    stageKV(0, 0);

    for (int t = 0; t < 32; t++) {
        const int bi = t & 1;
        __syncthreads();                 // tile t ready (vmcnt drained); buf^1 free
        if (t < 31) stageKV((t + 1) << 6, bi ^ 1);   // issue next tile NOW

        // ---- K frags from LDS (shared by all waves) + QK^T ----
        short8 kf[4][2];
#pragma unroll
        for (int nb = 0; nb < 4; nb++) {
            kf[nb][0] = *(const short8*)(&Ks[bi][0][nb * 16 + l15][quad * 8]);
            kf[nb][1] = *(const short8*)(&Ks[bi][1][nb * 16 + l15][quad * 8]);
        }
        f32x4 sacc[2][4];
#pragma unroll
        for (int nb = 0; nb < 4; nb++)
#pragma unroll
            for (int s = 0; s < 2; s++) {
                f32x4 zz; zz[0] = 0.f; zz[1] = 0.f; zz[2] = 0.f; zz[3] = 0.f;
                zz = __builtin_amdgcn_mfma_f32_16x16x32_bf16(qa[s][0], kf[nb][0], zz, 0, 0, 0);
                sacc[s][nb] = __builtin_amdgcn_mfma_f32_16x16x32_bf16(qa[s][1], kf[nb][1], zz, 0, 0, 0);
            }
        // ---- P = exp2(S'); partial row-sums; P -> wave-private LDS ----
#pragma unroll
        for (int s = 0; s < 2; s++)
#pragma unroll
            for (int r = 0; r < 4; r++)
#pragma unroll
                for (int nb = 0; nb < 4; nb++) {
                    float p = fexp2(sacc[s][nb][r]);
                    lsum[s][r] += p;
                    ps[w][s][(quad * 4 + r) * 72 + nb * 16 + l15] = f2bf_ru(p);
                }
        asm volatile("s_waitcnt lgkmcnt(0)" ::: "memory");
        short8 pa[2][2];
#pragma unroll
        for (int s = 0; s < 2; s++) {
            pa[s][0] = *(const short8*)(&ps[w][s][l15 * 72 + quad * 8]);
            pa[s][1] = *(const short8*)(&ps[w][s][l15 * 72 + 32 + quad * 8]);
        }
        // ---- V frags from LDS + PV ----
#pragma unroll
        for (int dd = 0; dd < 4; dd++) {
            short8 v0 = *(const short8*)(&Vs[bi][0][dd * 16 + l15][quad * 8]);
            short8 v1 = *(const short8*)(&Vs[bi][1][dd * 16 + l15][quad * 8]);
#pragma unroll
            for (int s = 0; s < 2; s++) {
                o[s][dd] = __builtin_amdgcn_mfma_f32_16x16x32_bf16(pa[s][0], v0, o[s][dd], 0, 0, 0);
                o[s][dd] = __builtin_amdgcn_mfma_f32_16x16x32_bf16(pa[s][1], v1, o[s][dd], 0, 0, 0);
            }
        }
    }

    // ---- deferred l reduction + epilogue ----
#pragma unroll
    for (int s = 0; s < 2; s++) {
#pragma unroll
        for (int r = 0; r < 4; r++) {
            float l = lsum[s][r];
            l += __shfl_xor(l, 1);
            l += __shfl_xor(l, 2);
            l += __shfl_xor(l, 4);
            l += __shfl_xor(l, 8);
            lsum[s][r] = 1.f / l;
        }
        float* orow = out + ((size_t)b * S_LEN + q0 + w * 32 + s * 16 + quad * 4) * DM + h * HD + l15;
#pragma unroll
        for (int r = 0; r < 4; r++)
#pragma unroll
            for (int dd = 0; dd < 4; dd++)
                orow[(size_t)r * DM + dd * 16] = o[s][dd][r] * lsum[s][r];
    }
}

// ---------------------------------------------------------------------------
// ws (56.6 MB): [0,6.3M) WT x3 bf16 | Qh | Kh | Vt (16.8M each)
// ---------------------------------------------------------------------------
extern "C" void kernel_launch(void* const* d_in, const int* in_sizes, int n_in,
                              void* d_out, int out_size, void* d_ws, size_t ws_size,
                              hipStream_t stream) {
    const float* query  = (const float*)d_in[0];
    const float* key_in = (const float*)d_in[1];
    const float* value  = (const float*)d_in[2];
    const float* Wq = (const float*)d_in[3];
    const float* bq = (const float*)d_in[4];
    const float* Wk = (const float*)d_in[5];
    const float* bk = (const float*)d_in[6];
    const float* Wv = (const float*)d_in[7];
    const float* bv = (const float*)d_in[8];

    short* wt = (short*)d_ws;
    short* Qh = wt + 3 * 1048576;
    short* Kh = Qh + 8388608;
    short* Vt = Kh + 8388608;
    float* out = (float*)d_out;

    const float QSCALE = 0.125f * 1.44269504088896340736f;  // 1/sqrt(64) * log2(e)

    wt_kernel<<<dim3(32, 32, 3), dim3(32, 8), 0, stream>>>(Wq, Wk, Wv, wt);
    projf_kernel<<<dim3(768), 512, 0, stream>>>(query, key_in, value, wt,
                                                bq, bk, bv, Qh, Kh, Vt, QSCALE);
    attn_kernel<<<dim3(512), 512, 0, stream>>>(Qh, Kh, Vt, out);
}